// Round 10
// baseline (1792.824 us; speedup 1.0000x reference)
//
#include <hip/hip_runtime.h>
#include <stdint.h>

#define E4M3_MAX 448.0f

typedef float f32x4 __attribute__((ext_vector_type(4)));
typedef int   i32x4 __attribute__((ext_vector_type(4)));
typedef int   i32x8 __attribute__((ext_vector_type(8)));

// ---------------------------------------------------------------------------
// async global -> LDS, 16 bytes per lane. LDS dest stays LINEAR (HW
// constraint); T2 swizzle applied by pre-swizzling the GLOBAL source column
// and swizzling the LDS READ offset with the same involution (rule #21).
// ---------------------------------------------------------------------------
__device__ __forceinline__ void gload_lds16(const void* g, void* l) {
    __builtin_amdgcn_global_load_lds(
        (__attribute__((address_space(1))) void*)(void*)g,
        (__attribute__((address_space(3))) void*)l,
        16, 0, 0);
}

__device__ __forceinline__ uint32_t quant4(float a, float b, float c, float d) {
    a = fminf(fmaxf(a, -E4M3_MAX), E4M3_MAX);
    b = fminf(fmaxf(b, -E4M3_MAX), E4M3_MAX);
    c = fminf(fmaxf(c, -E4M3_MAX), E4M3_MAX);
    d = fminf(fmaxf(d, -E4M3_MAX), E4M3_MAX);
    int q = 0;
    q = __builtin_amdgcn_cvt_pk_fp8_f32(a, b, q, false);
    q = __builtin_amdgcn_cvt_pk_fp8_f32(c, d, q, true);
    return (uint32_t)q;
}

__global__ void quant_x_kernel(const float* __restrict__ x,
                               const float* __restrict__ scale_p,
                               uint4* __restrict__ xq, int n16) {
    const float inv = 1.0f / scale_p[0];
    const int stride = gridDim.x * blockDim.x;
    for (int i = blockIdx.x * blockDim.x + threadIdx.x; i < n16; i += stride) {
        const float4* p = (const float4*)x + (size_t)i * 4;
        float4 v0 = p[0], v1 = p[1], v2 = p[2], v3 = p[3];
        uint4 q;
        q.x = quant4(v0.x * inv, v0.y * inv, v0.z * inv, v0.w * inv);
        q.y = quant4(v1.x * inv, v1.y * inv, v1.z * inv, v1.w * inv);
        q.z = quant4(v2.x * inv, v2.y * inv, v2.z * inv, v2.w * inv);
        q.w = quant4(v3.x * inv, v3.y * inv, v3.z * inv, v3.w * inv);
        xq[i] = q;
    }
}

// ---------------------------------------------------------------------------
// quantize w into MFMA-FRAGMENT-SHUFFLED layout so the GEMM can load B
// fragments directly global->register with perfectly coalesced dwordx4.
// Element (n, k):  nf=n>>4, r=n&15, kt=k>>7, kg=(k>>5)&3, koff=k&31
//   dst_byte = ((nf*nkt + kt)*64 + kg*16 + r)*32 + koff
// ---------------------------------------------------------------------------
__global__ void quant_w_kernel(const float* __restrict__ w,
                               const float* __restrict__ wsc,
                               uint8_t* __restrict__ wq,
                               int Nrows, int K, int chunkRows) {
    const int nkt = K >> 7;
    const int n32 = Nrows * (K >> 5);
    const int stride = gridDim.x * blockDim.x;
    for (int i = blockIdx.x * blockDim.x + threadIdx.x; i < n32; i += stride) {
        const int n  = i % Nrows;
        const int k0 = (i / Nrows) << 5;
        const float inv = 1.0f / wsc[n / chunkRows];
        const float4* p = (const float4*)(w + (size_t)n * K + k0);
        uint4 qa, qb;
        {
            float4 v0 = p[0], v1 = p[1], v2 = p[2], v3 = p[3];
            qa.x = quant4(v0.x * inv, v0.y * inv, v0.z * inv, v0.w * inv);
            qa.y = quant4(v1.x * inv, v1.y * inv, v1.z * inv, v1.w * inv);
            qa.z = quant4(v2.x * inv, v2.y * inv, v2.z * inv, v2.w * inv);
            qa.w = quant4(v3.x * inv, v3.y * inv, v3.z * inv, v3.w * inv);
        }
        {
            float4 v0 = p[4], v1 = p[5], v2 = p[6], v3 = p[7];
            qb.x = quant4(v0.x * inv, v0.y * inv, v0.z * inv, v0.w * inv);
            qb.y = quant4(v1.x * inv, v1.y * inv, v1.z * inv, v1.w * inv);
            qb.z = quant4(v2.x * inv, v2.y * inv, v2.z * inv, v2.w * inv);
            qb.w = quant4(v3.x * inv, v3.y * inv, v3.z * inv, v3.w * inv);
        }
        const int kt = k0 >> 7, kg = (k0 >> 5) & 3, r = n & 15, nf = n >> 4;
        uint8_t* dst = wq + (((size_t)nf * nkt + kt) * 64 + kg * 16 + r) * 32;
        *(uint4*)dst = qa;
        *(uint4*)(dst + 16) = qb;
    }
}

__device__ __forceinline__ i32x8 read_frag(const uint8_t* base, int o0, int o1) {
    i32x4 lo = *(const i32x4*)(base + o0);
    i32x4 hi = *(const i32x4*)(base + o1);
    return __builtin_shufflevector(lo, hi, 0, 1, 2, 3, 4, 5, 6, 7);
}

__device__ __forceinline__ i32x8 load_bfrag(const uint8_t* p) {
    i32x4 lo = *(const i32x4*)p;
    i32x4 hi = *(const i32x4*)(p + 16);
    return __builtin_shufflevector(lo, hi, 0, 1, 2, 3, 4, 5, 6, 7);
}

#define MFMA_MX(a, b, c) \
    __builtin_amdgcn_mfma_scale_f32_16x16x128_f8f6f4( \
        (a), (b), (c), 0, 0, 0, 0x7F7F7F7F, 0, 0x7F7F7F7F)

#define WAIT_LGKM(n)                                            \
    do {                                                        \
        asm volatile("s_waitcnt lgkmcnt(" #n ")" ::: "memory"); \
        __builtin_amdgcn_sched_barrier(0);                      \
    } while (0)

#define WAIT_VM(n)                                              \
    do {                                                        \
        asm volatile("s_waitcnt vmcnt(" #n ")" ::: "memory");   \
        __builtin_amdgcn_sched_barrier(0);                      \
    } while (0)

// ---------------------------------------------------------------------------
// fp8-MX GEMM, 256x256 tile, 8 waves (2Mx4N), wave-tile 128x64.
// Round-10 = round-9 schedule with arch-VGPR pressure cut below the 128
// cliff (512-thr block => 2 waves/EU => 256 unified regs; acc=128 AGPR
// leaves 128 arch):
//   - A-pipeline depth 1: 8 groups/K-tile, group i = {lgkm(2) [frag i
//     ready, i+1 in flight]; 4 MFMA; issue frag i+2}. Max 3 live A frags.
//   - B(t) in named bc0..3, B(t+1) prefetched into bn0..3 (64 regs).
//   - vmcnt ledger (issue order: stage 4, B(t+1) 8):
//       g0:      vmcnt(12) -> retires B(t) only
//       iterend: vmcnt(8)  -> retires stage(t+1); B(t+1) crosses barrier
// ---------------------------------------------------------------------------
#define BM 256
#define BN 256
#define BKB 128

#define MFMA_GROUP(AI, MI)                                \
    do {                                                  \
        __builtin_amdgcn_s_setprio(1);                    \
        acc[MI][0] = MFMA_MX(AI, bcc0, acc[MI][0]);       \
        acc[MI][1] = MFMA_MX(AI, bcc1, acc[MI][1]);       \
        acc[MI][2] = MFMA_MX(AI, bcc2, acc[MI][2]);       \
        acc[MI][3] = MFMA_MX(AI, bcc3, acc[MI][3]);       \
        __builtin_amdgcn_s_setprio(0);                    \
    } while (0)

#define TILE_ITER(T, BC0, BC1, BC2, BC3, BN0, BN1, BN2, BN3)                   \
    do {                                                                       \
        const int  cur = (T) & 1;                                              \
        const bool pre = ((T) + 1 < nkt);                                      \
        const uint8_t* pa = &As[cur][0] + (wm * 128 + lr) * BKB;               \
        i32x8 bcc0 = BC0, bcc1 = BC1, bcc2 = BC2, bcc3 = BC3;                  \
        i32x8 a0 = read_frag(pa,            off0, off1);                       \
        i32x8 a1 = read_frag(pa + 16 * BKB, off0, off1);                       \
        if (pre) {                                                             \
            stage(cur ^ 1, ((T) + 1) * BKB);                                   \
            __builtin_amdgcn_sched_barrier(0);                                 \
            const size_t boff = (size_t)((T) + 1) * 2048;                      \
            BN0 = load_bfrag(bB0 + boff);                                      \
            BN1 = load_bfrag(bB1 + boff);                                      \
            BN2 = load_bfrag(bB2 + boff);                                      \
            BN3 = load_bfrag(bB3 + boff);                                      \
            __builtin_amdgcn_sched_barrier(0);                                 \
        }                                                                      \
        if (pre) { WAIT_VM(12); } else { WAIT_VM(0); }                         \
        WAIT_LGKM(2);  MFMA_GROUP(a0, 0);                                      \
        i32x8 a2 = read_frag(pa + 32 * BKB, off0, off1);                       \
        WAIT_LGKM(2);  MFMA_GROUP(a1, 1);                                      \
        i32x8 a3 = read_frag(pa + 48 * BKB, off0, off1);                       \
        WAIT_LGKM(2);  MFMA_GROUP(a2, 2);                                      \
        i32x8 a4 = read_frag(pa + 64 * BKB, off0, off1);                       \
        WAIT_LGKM(2);  MFMA_GROUP(a3, 3);                                      \
        i32x8 a5 = read_frag(pa + 80 * BKB, off0, off1);                       \
        WAIT_LGKM(2);  MFMA_GROUP(a4, 4);                                      \
        i32x8 a6 = read_frag(pa + 96 * BKB, off0, off1);                       \
        WAIT_LGKM(2);  MFMA_GROUP(a5, 5);                                      \
        i32x8 a7 = read_frag(pa + 112 * BKB, off0, off1);                      \
        WAIT_LGKM(2);  MFMA_GROUP(a6, 6);                                      \
        WAIT_LGKM(0);  MFMA_GROUP(a7, 7);                                      \
        if (pre) { WAIT_VM(8); } else { WAIT_VM(0); }                          \
        __builtin_amdgcn_s_barrier();                                          \
    } while (0)

__global__ __launch_bounds__(512, 2) void gemm_fp8_kernel(
    const uint8_t* __restrict__ Aq, const uint8_t* __restrict__ Bq,
    const float* __restrict__ bias, const float* __restrict__ isp,
    const float* __restrict__ wsc, float* __restrict__ out,
    int M, int N, int K, int ocPerChunk) {
    __shared__ __align__(16) uint8_t As[2][BM * BKB];   // A only, 2 x 32 KB

    const int tid  = threadIdx.x;
    const int lane = tid & 63;
    const int wid  = tid >> 6;   // 0..7
    const int wm   = wid >> 2;   // 0..1  (M half)
    const int wn   = wid & 3;    // 0..3  (N quarter)

    // T1 XCD swizzle, by-inner chunking: consecutive blocks on an XCD share
    // bx -> the XCD's CUs work on few B-panels (L2-fit).
    const int nby   = M / BM;
    const int chunk = nby >> 3;            // by-rows per XCD
    const int xcd   = blockIdx.x & 7;
    const int local = blockIdx.x >> 3;
    const int bx    = local / chunk;
    const int by    = xcd * chunk + (local % chunk);
    const int m0    = by * BM;
    const int n0    = bx * BN;

    const int lr   = lane & 15;
    const int sw   = (lr & 7) << 4;
    const int off0 = ((lane >> 4) * 32) ^ sw;
    const int off1 = off0 ^ 16;

    f32x4 acc[8][4] = {};

    const int nkt = K / BKB;

    // B fragment bases: frag ni of wave wn at tile t = bBni + t*2048,
    // lane-contiguous 32 B.
    const size_t bstr = (size_t)nkt * 2048;
    const uint8_t* bB0 =
        Bq + ((size_t)((n0 >> 4) + wn * 4)) * bstr + lane * 32;
    const uint8_t* bB1 = bB0 + bstr;
    const uint8_t* bB2 = bB1 + bstr;
    const uint8_t* bB3 = bB2 + bstr;

    // stage A K-tile (k-offset kt) into buffer b: 4 x gload_lds16 per thread
    auto stage = [&](int b, int kt) {
#pragma unroll
        for (int i = 0; i < 4; ++i) {
            const int idx = i * 512 + tid;                 // 0..2047
            const int row = idx >> 3;                      // 0..255
            const int col = ((idx & 7) * 16) ^ ((row & 7) << 4);
            gload_lds16(Aq + (size_t)(m0 + row) * K + kt + col,
                        &As[b][0] + idx * 16);
        }
    };

    i32x8 bc0, bc1, bc2, bc3, bn0, bn1, bn2, bn3;

    // prologue: A tile 0 -> LDS, B tile 0 -> bc*
    stage(0, 0);
    bc0 = load_bfrag(bB0);
    bc1 = load_bfrag(bB1);
    bc2 = load_bfrag(bB2);
    bc3 = load_bfrag(bB3);
    asm volatile("s_waitcnt vmcnt(0)" ::: "memory");
    __builtin_amdgcn_s_barrier();

    for (int t = 0; t < nkt; t += 2) {
        TILE_ITER(t,     bc0, bc1, bc2, bc3, bn0, bn1, bn2, bn3);
        TILE_ITER(t + 1, bn0, bn1, bn2, bn3, bc0, bc1, bc2, bc3);
    }

    // ---- epilogue: dequant + bias (C/D: col=lane&15, row=(lane>>4)*4+j) ----
    const float is = isp[0];
#pragma unroll
    for (int ni = 0; ni < 4; ni++) {
        const int cidx = n0 + wn * 64 + ni * 16 + lr;
        const float sc = is * wsc[cidx / ocPerChunk];
        const float bs = bias[cidx];
#pragma unroll
        for (int mi = 0; mi < 8; mi++) {
            const int rbase = m0 + wm * 128 + mi * 16 + (lane >> 4) * 4;
#pragma unroll
            for (int j = 0; j < 4; j++)
                out[(size_t)(rbase + j) * N + cidx] = acc[mi][ni][j] * sc + bs;
        }
    }
}

// ---------------------------------------------------------------------------
extern "C" void kernel_launch(void* const* d_in, const int* in_sizes, int n_in,
                              void* d_out, int out_size, void* d_ws, size_t ws_size,
                              hipStream_t stream) {
    const float* x        = (const float*)d_in[0];
    const float* w        = (const float*)d_in[1];
    const float* bias     = (const float*)d_in[2];
    const float* in_scale = (const float*)d_in[3];
    const float* w_scales = (const float*)d_in[4];
    float* out = (float*)d_out;

    const int N = in_sizes[2];               // 4096
    const int K = in_sizes[1] / N;           // 4096
    const int M = in_sizes[0] / K;           // 16384
    const int CHUNKS = in_sizes[4];          // 4
    const int ocPerChunk = N / CHUNKS;       // 1024

    uint8_t* xq = (uint8_t*)d_ws;            // M*K bytes
    uint8_t* wq = xq + (size_t)M * K;        // N*K bytes (fragment-shuffled)

    const int xn16 = (int)(((size_t)M * K) / 16);

    quant_x_kernel<<<2048, 256, 0, stream>>>(x, in_scale, (uint4*)xq, xn16);
    quant_w_kernel<<<2048, 256, 0, stream>>>(w, w_scales, wq, N, K, ocPerChunk);

    const int nblk = (M / BM) * (N / BN);    // 64 * 16 = 1024
    gemm_fp8_kernel<<<dim3(nblk), 512, 0, stream>>>(xq, wq, bias, in_scale,
                                                    w_scales, out, M, N, K,
                                                    ocPerChunk);
}

// Round 11
// 1752.579 us; speedup vs baseline: 1.0230x; 1.0230x over previous
//
#include <hip/hip_runtime.h>
#include <stdint.h>

#define E4M3_MAX 448.0f

typedef float f32x4 __attribute__((ext_vector_type(4)));
typedef int   i32x4 __attribute__((ext_vector_type(4)));
typedef int   i32x8 __attribute__((ext_vector_type(8)));

// ---------------------------------------------------------------------------
// async global -> LDS, 16 bytes per lane. LDS dest stays LINEAR (HW
// constraint); T2 swizzle applied by pre-swizzling the GLOBAL source column
// and swizzling the LDS READ offset with the same involution (rule #21).
// ---------------------------------------------------------------------------
__device__ __forceinline__ void gload_lds16(const void* g, void* l) {
    __builtin_amdgcn_global_load_lds(
        (__attribute__((address_space(1))) void*)(void*)g,
        (__attribute__((address_space(3))) void*)l,
        16, 0, 0);
}

__device__ __forceinline__ uint32_t quant4(float a, float b, float c, float d) {
    a = fminf(fmaxf(a, -E4M3_MAX), E4M3_MAX);
    b = fminf(fmaxf(b, -E4M3_MAX), E4M3_MAX);
    c = fminf(fmaxf(c, -E4M3_MAX), E4M3_MAX);
    d = fminf(fmaxf(d, -E4M3_MAX), E4M3_MAX);
    int q = 0;
    q = __builtin_amdgcn_cvt_pk_fp8_f32(a, b, q, false);
    q = __builtin_amdgcn_cvt_pk_fp8_f32(c, d, q, true);
    return (uint32_t)q;
}

__global__ void quant_x_kernel(const float* __restrict__ x,
                               const float* __restrict__ scale_p,
                               uint4* __restrict__ xq, int n16) {
    const float inv = 1.0f / scale_p[0];
    const int stride = gridDim.x * blockDim.x;
    for (int i = blockIdx.x * blockDim.x + threadIdx.x; i < n16; i += stride) {
        const float4* p = (const float4*)x + (size_t)i * 4;
        float4 v0 = p[0], v1 = p[1], v2 = p[2], v3 = p[3];
        uint4 q;
        q.x = quant4(v0.x * inv, v0.y * inv, v0.z * inv, v0.w * inv);
        q.y = quant4(v1.x * inv, v1.y * inv, v1.z * inv, v1.w * inv);
        q.z = quant4(v2.x * inv, v2.y * inv, v2.z * inv, v2.w * inv);
        q.w = quant4(v3.x * inv, v3.y * inv, v3.z * inv, v3.w * inv);
        xq[i] = q;
    }
}

// ---------------------------------------------------------------------------
// quantize w into MFMA-FRAGMENT-SHUFFLED layout:
//   dst_byte = ((nf*nkt + kt)*64 + kg*16 + r)*32 + koff
// (nf=n>>4, r=n&15, kt=k>>7, kg=(k>>5)&3, koff=k&31)
// ---------------------------------------------------------------------------
__global__ void quant_w_kernel(const float* __restrict__ w,
                               const float* __restrict__ wsc,
                               uint8_t* __restrict__ wq,
                               int Nrows, int K, int chunkRows) {
    const int nkt = K >> 7;
    const int n32 = Nrows * (K >> 5);
    const int stride = gridDim.x * blockDim.x;
    for (int i = blockIdx.x * blockDim.x + threadIdx.x; i < n32; i += stride) {
        const int n  = i % Nrows;
        const int k0 = (i / Nrows) << 5;
        const float inv = 1.0f / wsc[n / chunkRows];
        const float4* p = (const float4*)(w + (size_t)n * K + k0);
        uint4 qa, qb;
        {
            float4 v0 = p[0], v1 = p[1], v2 = p[2], v3 = p[3];
            qa.x = quant4(v0.x * inv, v0.y * inv, v0.z * inv, v0.w * inv);
            qa.y = quant4(v1.x * inv, v1.y * inv, v1.z * inv, v1.w * inv);
            qa.z = quant4(v2.x * inv, v2.y * inv, v2.z * inv, v2.w * inv);
            qa.w = quant4(v3.x * inv, v3.y * inv, v3.z * inv, v3.w * inv);
        }
        {
            float4 v0 = p[4], v1 = p[5], v2 = p[6], v3 = p[7];
            qb.x = quant4(v0.x * inv, v0.y * inv, v0.z * inv, v0.w * inv);
            qb.y = quant4(v1.x * inv, v1.y * inv, v1.z * inv, v1.w * inv);
            qb.z = quant4(v2.x * inv, v2.y * inv, v2.z * inv, v2.w * inv);
            qb.w = quant4(v3.x * inv, v3.y * inv, v3.z * inv, v3.w * inv);
        }
        const int kt = k0 >> 7, kg = (k0 >> 5) & 3, r = n & 15, nf = n >> 4;
        uint8_t* dst = wq + (((size_t)nf * nkt + kt) * 64 + kg * 16 + r) * 32;
        *(uint4*)dst = qa;
        *(uint4*)(dst + 16) = qb;
    }
}

__device__ __forceinline__ i32x8 load_bfrag(const uint8_t* p) {
    i32x4 lo = *(const i32x4*)p;
    i32x4 hi = *(const i32x4*)(p + 16);
    return __builtin_shufflevector(lo, hi, 0, 1, 2, 3, 4, 5, 6, 7);
}

#define MFMA_MX(a, b, c) \
    __builtin_amdgcn_mfma_scale_f32_16x16x128_f8f6f4( \
        (a), (b), (c), 0, 0, 0, 0x7F7F7F7F, 0, 0x7F7F7F7F)

#define WAIT_LGKM(n)                                            \
    do {                                                        \
        asm volatile("s_waitcnt lgkmcnt(" #n ")" ::: "memory"); \
        __builtin_amdgcn_sched_barrier(0);                      \
    } while (0)

#define WAIT_VM(n)                                              \
    do {                                                        \
        asm volatile("s_waitcnt vmcnt(" #n ")" ::: "memory");   \
        __builtin_amdgcn_sched_barrier(0);                      \
    } while (0)

// ---------------------------------------------------------------------------
// fp8-MX GEMM, 256x256 tile, 8 waves (2Mx4N), wave-tile 128x64.
// Round-11 = round-10 schedule, minimal live set (target < 128 arch VGPR):
//   - NO register copies: MFMA reads BC0..3 directly; dbuf rotation by
//     macro name-swap.
//   - A frag reads: two 32-bit LDS bases (pa0/pa1); buffer+frag selection
//     via compile-time ds offset imm (BOFF + frag*2048 <= 47104 < 64K).
//   - stage: one global base + uniform i*64K offsets; swizzle col folded
//     into the base (i-invariant).
//   - B: one global base + uniform ni*bstr + t*2048 offsets.
//   - vmcnt ledger (issue: stage 4, B(t+1) 8): g0 waits vmcnt(12) = B(t)
//     retired; iter-end vmcnt(8) = stage retired, B(t+1) crosses barrier.
//   - lgkm(2) A cadence: max 3 live A frags.
// ---------------------------------------------------------------------------
#define BM 256
#define BN 256
#define BKB 128

// read A fragment at compile-time byte offset COFF from the two bases
#define RF(COFF)                                                          \
    (__extension__({                                                      \
        i32x4 lo_ = *(const i32x4*)(pa0 + (COFF));                        \
        i32x4 hi_ = *(const i32x4*)(pa1 + (COFF));                        \
        __builtin_shufflevector(lo_, hi_, 0, 1, 2, 3, 4, 5, 6, 7);        \
    }))

#define MFMA_G(AI, MI, BC0, BC1, BC2, BC3)            \
    do {                                              \
        __builtin_amdgcn_s_setprio(1);                \
        acc[MI][0] = MFMA_MX(AI, BC0, acc[MI][0]);    \
        acc[MI][1] = MFMA_MX(AI, BC1, acc[MI][1]);    \
        acc[MI][2] = MFMA_MX(AI, BC2, acc[MI][2]);    \
        acc[MI][3] = MFMA_MX(AI, BC3, acc[MI][3]);    \
        __builtin_amdgcn_s_setprio(0);                \
    } while (0)

#define TILE_ITER(T, BOFF, SOFF, BC0, BC1, BC2, BC3, BN0, BN1, BN2, BN3)       \
    do {                                                                       \
        const bool pre = ((T) + 1 < nkt);                                      \
        i32x8 a0 = RF((BOFF) + 0 * 2048);                                      \
        i32x8 a1 = RF((BOFF) + 1 * 2048);                                      \
        if (pre) {                                                             \
            const size_t gk = (size_t)((T) + 1) * BKB;                         \
            gload_lds16(gA + gk,              ldsW + (SOFF));                  \
            gload_lds16(gA + row64K + gk,     ldsW + (SOFF) + 8192);           \
            gload_lds16(gA + 2 * row64K + gk, ldsW + (SOFF) + 16384);          \
            gload_lds16(gA + 3 * row64K + gk, ldsW + (SOFF) + 24576);          \
            __builtin_amdgcn_sched_barrier(0);                                 \
            const size_t bo = (size_t)((T) + 1) * 2048;                        \
            BN0 = load_bfrag(bB + bo);                                         \
            BN1 = load_bfrag(bB + bstr + bo);                                  \
            BN2 = load_bfrag(bB + 2 * bstr + bo);                              \
            BN3 = load_bfrag(bB + 3 * bstr + bo);                              \
            __builtin_amdgcn_sched_barrier(0);                                 \
            WAIT_VM(12);                                                       \
        } else {                                                               \
            WAIT_VM(0);                                                        \
        }                                                                      \
        WAIT_LGKM(2); MFMA_G(a0, 0, BC0, BC1, BC2, BC3);                       \
        i32x8 a2 = RF((BOFF) + 2 * 2048);                                      \
        WAIT_LGKM(2); MFMA_G(a1, 1, BC0, BC1, BC2, BC3);                       \
        i32x8 a3 = RF((BOFF) + 3 * 2048);                                      \
        WAIT_LGKM(2); MFMA_G(a2, 2, BC0, BC1, BC2, BC3);                       \
        i32x8 a4 = RF((BOFF) + 4 * 2048);                                      \
        WAIT_LGKM(2); MFMA_G(a3, 3, BC0, BC1, BC2, BC3);                       \
        i32x8 a5 = RF((BOFF) + 5 * 2048);                                      \
        WAIT_LGKM(2); MFMA_G(a4, 4, BC0, BC1, BC2, BC3);                       \
        i32x8 a6 = RF((BOFF) + 6 * 2048);                                      \
        WAIT_LGKM(2); MFMA_G(a5, 5, BC0, BC1, BC2, BC3);                       \
        i32x8 a7 = RF((BOFF) + 7 * 2048);                                      \
        WAIT_LGKM(2); MFMA_G(a6, 6, BC0, BC1, BC2, BC3);                       \
        WAIT_LGKM(0); MFMA_G(a7, 7, BC0, BC1, BC2, BC3);                       \
        if (pre) { WAIT_VM(8); } else { WAIT_VM(0); }                          \
        __builtin_amdgcn_s_barrier();                                          \
    } while (0)

__global__ __launch_bounds__(512, 2) void gemm_fp8_kernel(
    const uint8_t* __restrict__ Aq, const uint8_t* __restrict__ Bq,
    const float* __restrict__ bias, const float* __restrict__ isp,
    const float* __restrict__ wsc, float* __restrict__ out,
    int M, int N, int K, int ocPerChunk) {
    __shared__ __align__(16) uint8_t As[2][BM * BKB];   // A only, 2 x 32 KB

    const int tid  = threadIdx.x;
    const int lane = tid & 63;
    const int wid  = tid >> 6;   // 0..7
    const int wm   = wid >> 2;   // 0..1  (M half)
    const int wn   = wid & 3;    // 0..3  (N quarter)

    // T1 XCD swizzle, by-inner chunking
    const int nby   = M / BM;
    const int chunk = nby >> 3;
    const int xcd   = blockIdx.x & 7;
    const int local = blockIdx.x >> 3;
    const int bx    = local / chunk;
    const int by    = xcd * chunk + (local % chunk);
    const int m0    = by * BM;
    const int n0    = bx * BN;

    const int lr   = lane & 15;
    const int sw   = (lr & 7) << 4;
    const int off0 = ((lane >> 4) * 32) ^ sw;
    const int off1 = off0 ^ 16;

    f32x4 acc[8][4] = {};

    const int nkt = K / BKB;

    // ---- compact addressing ----
    uint8_t* AsF = &As[0][0];
    // A LDS read bases (32-bit LDS addrs after compiler lowering)
    const uint8_t* pa0 = AsF + (wm * 128 + lr) * BKB + off0;
    const uint8_t* pa1 = AsF + (wm * 128 + lr) * BKB + off1;
    // stage: global base (swizzle col is i-invariant) + LDS write base
    const int scol = ((tid & 7) * 16) ^ (((tid >> 3) & 7) << 4);
    const uint8_t* gA = Aq + (size_t)(m0 + (tid >> 3)) * K + scol;
    const size_t row64K = (size_t)64 * K;
    uint8_t* ldsW = AsF + tid * 16;
    // B base: frag ni of wave wn at tile t = bB + ni*bstr + t*2048 + lane*32
    const size_t bstr = (size_t)nkt * 2048;
    const uint8_t* bB = Bq + ((size_t)((n0 >> 4) + wn * 4)) * bstr + lane * 32;

    i32x8 bc0, bc1, bc2, bc3, bn0, bn1, bn2, bn3;

    // prologue: A tile 0 -> LDS buf0, B tile 0 -> bc*
    gload_lds16(gA,              ldsW);
    gload_lds16(gA + row64K,     ldsW + 8192);
    gload_lds16(gA + 2 * row64K, ldsW + 16384);
    gload_lds16(gA + 3 * row64K, ldsW + 24576);
    bc0 = load_bfrag(bB);
    bc1 = load_bfrag(bB + bstr);
    bc2 = load_bfrag(bB + 2 * bstr);
    bc3 = load_bfrag(bB + 3 * bstr);
    asm volatile("s_waitcnt vmcnt(0)" ::: "memory");
    __builtin_amdgcn_s_barrier();

    for (int t = 0; t < nkt; t += 2) {
        TILE_ITER(t,     0,     32768, bc0, bc1, bc2, bc3, bn0, bn1, bn2, bn3);
        TILE_ITER(t + 1, 32768, 0,     bn0, bn1, bn2, bn3, bc0, bc1, bc2, bc3);
    }

    // ---- epilogue: dequant + bias (C/D: col=lane&15, row=(lane>>4)*4+j) ----
    const float is = isp[0];
#pragma unroll
    for (int ni = 0; ni < 4; ni++) {
        const int cidx = n0 + wn * 64 + ni * 16 + lr;
        const float sc = is * wsc[cidx / ocPerChunk];
        const float bs = bias[cidx];
#pragma unroll
        for (int mi = 0; mi < 8; mi++) {
            const int rbase = m0 + wm * 128 + mi * 16 + (lane >> 4) * 4;
#pragma unroll
            for (int j = 0; j < 4; j++)
                out[(size_t)(rbase + j) * N + cidx] = acc[mi][ni][j] * sc + bs;
        }
    }
}

// ---------------------------------------------------------------------------
extern "C" void kernel_launch(void* const* d_in, const int* in_sizes, int n_in,
                              void* d_out, int out_size, void* d_ws, size_t ws_size,
                              hipStream_t stream) {
    const float* x        = (const float*)d_in[0];
    const float* w        = (const float*)d_in[1];
    const float* bias     = (const float*)d_in[2];
    const float* in_scale = (const float*)d_in[3];
    const float* w_scales = (const float*)d_in[4];
    float* out = (float*)d_out;

    const int N = in_sizes[2];               // 4096
    const int K = in_sizes[1] / N;           // 4096
    const int M = in_sizes[0] / K;           // 16384
    const int CHUNKS = in_sizes[4];          // 4
    const int ocPerChunk = N / CHUNKS;       // 1024

    uint8_t* xq = (uint8_t*)d_ws;            // M*K bytes
    uint8_t* wq = xq + (size_t)M * K;        // N*K bytes (fragment-shuffled)

    const int xn16 = (int)(((size_t)M * K) / 16);

    quant_x_kernel<<<2048, 256, 0, stream>>>(x, in_scale, (uint4*)xq, xn16);
    quant_w_kernel<<<2048, 256, 0, stream>>>(w, w_scales, wq, N, K, ocPerChunk);

    const int nblk = (M / BM) * (N / BN);    // 64 * 16 = 1024
    gemm_fp8_kernel<<<dim3(nblk), 512, 0, stream>>>(xq, wq, bias, in_scale,
                                                    w_scales, out, M, N, K,
                                                    ocPerChunk);
}

// Round 13
// 372.162 us; speedup vs baseline: 4.8173x; 4.7092x over previous
//
#include <hip/hip_runtime.h>
#include <stdint.h>

#define E4M3_MAX 448.0f

typedef float f32x4 __attribute__((ext_vector_type(4)));
typedef int   i32x4 __attribute__((ext_vector_type(4)));
typedef int   i32x8 __attribute__((ext_vector_type(8)));

// ---------------------------------------------------------------------------
// async global -> LDS, 16 bytes per lane. LDS dest stays LINEAR (HW
// constraint); T2 swizzle applied by pre-swizzling the GLOBAL source column
// and swizzling the LDS READ offset with the same involution (rule #21).
// ---------------------------------------------------------------------------
__device__ __forceinline__ void gload_lds16(const void* g, void* l) {
    __builtin_amdgcn_global_load_lds(
        (__attribute__((address_space(1))) void*)(void*)g,
        (__attribute__((address_space(3))) void*)l,
        16, 0, 0);
}

__device__ __forceinline__ uint32_t quant4(float a, float b, float c, float d) {
    a = fminf(fmaxf(a, -E4M3_MAX), E4M3_MAX);
    b = fminf(fmaxf(b, -E4M3_MAX), E4M3_MAX);
    c = fminf(fmaxf(c, -E4M3_MAX), E4M3_MAX);
    d = fminf(fmaxf(d, -E4M3_MAX), E4M3_MAX);
    int q = 0;
    q = __builtin_amdgcn_cvt_pk_fp8_f32(a, b, q, false);
    q = __builtin_amdgcn_cvt_pk_fp8_f32(c, d, q, true);
    return (uint32_t)q;
}

__global__ void quant_x_kernel(const float* __restrict__ x,
                               const float* __restrict__ scale_p,
                               uint4* __restrict__ xq, int n16) {
    const float inv = 1.0f / scale_p[0];
    const int stride = gridDim.x * blockDim.x;
    for (int i = blockIdx.x * blockDim.x + threadIdx.x; i < n16; i += stride) {
        const float4* p = (const float4*)x + (size_t)i * 4;
        float4 v0 = p[0], v1 = p[1], v2 = p[2], v3 = p[3];
        uint4 q;
        q.x = quant4(v0.x * inv, v0.y * inv, v0.z * inv, v0.w * inv);
        q.y = quant4(v1.x * inv, v1.y * inv, v1.z * inv, v1.w * inv);
        q.z = quant4(v2.x * inv, v2.y * inv, v2.z * inv, v2.w * inv);
        q.w = quant4(v3.x * inv, v3.y * inv, v3.z * inv, v3.w * inv);
        xq[i] = q;
    }
}

__global__ void quant_w_kernel(const float* __restrict__ w,
                               const float* __restrict__ wsc,
                               uint4* __restrict__ wq, int n16, int chunk16) {
    const int stride = gridDim.x * blockDim.x;
    for (int i = blockIdx.x * blockDim.x + threadIdx.x; i < n16; i += stride) {
        const float inv = 1.0f / wsc[i / chunk16];
        const float4* p = (const float4*)w + (size_t)i * 4;
        float4 v0 = p[0], v1 = p[1], v2 = p[2], v3 = p[3];
        uint4 q;
        q.x = quant4(v0.x * inv, v0.y * inv, v0.z * inv, v0.w * inv);
        q.y = quant4(v1.x * inv, v1.y * inv, v1.z * inv, v1.w * inv);
        q.z = quant4(v2.x * inv, v2.y * inv, v2.z * inv, v2.w * inv);
        q.w = quant4(v3.x * inv, v3.y * inv, v3.z * inv, v3.w * inv);
        wq[i] = q;
    }
}

__device__ __forceinline__ i32x8 read_frag(const uint8_t* base, int o0, int o1) {
    i32x4 lo = *(const i32x4*)(base + o0);
    i32x4 hi = *(const i32x4*)(base + o1);
    return __builtin_shufflevector(lo, hi, 0, 1, 2, 3, 4, 5, 6, 7);
}

#define MFMA_MX(a, b, c) \
    __builtin_amdgcn_mfma_scale_f32_16x16x128_f8f6f4( \
        (a), (b), (c), 0, 0, 0, 0x7F7F7F7F, 0, 0x7F7F7F7F)

#define WAIT_LGKM(n)                                          \
    do {                                                      \
        asm volatile("s_waitcnt lgkmcnt(" #n ")" ::: "memory"); \
        __builtin_amdgcn_sched_barrier(0);                    \
    } while (0)

// ---------------------------------------------------------------------------
// fp8-MX GEMM, 256x256 tile, 8 waves (2Mx4N), wave-tile 128x64.
// BKB=128 bytes = one K=128 MFMA step.  Round-6 schedule (verified best):
// counted-lgkmcnt register pipeline -> LDS pipe overlaps matrix pipe
// within each wave:
//   top barrier (tile t staged, buf[cur^1] free)
//   issue B(8 b128) + pair0(4) + pair1(4); issue stage(t+1) into cur^1
//   lgkmcnt(4)  -> B+pair0 ready, pair1 in flight   -> MFMA g0
//   issue pair2; lgkmcnt(4) -> pair1 ready          -> MFMA g1
//   issue pair3; lgkmcnt(4) -> pair2 ready          -> MFMA g2
//   lgkmcnt(0)  -> pair3 ready                      -> MFMA g3
//   vmcnt(0) (3+ phases of slack since stage issue); s_barrier
// ONE barrier per K-tile. lgkmcnt(0) before g3 retires all tile-t reads
// before any wave passes the barrier -> stage(t+1) WAR-safe.
// LDS byte map: LDS[row][c] = global[row][c ^ ((row&7)<<4)]  (T2).
// ---------------------------------------------------------------------------
#define BM 256
#define BN 256
#define BKB 128

__global__ __launch_bounds__(512, 2) void gemm_fp8_kernel(
    const uint8_t* __restrict__ Aq, const uint8_t* __restrict__ Bq,
    const float* __restrict__ bias, const float* __restrict__ isp,
    const float* __restrict__ wsc, float* __restrict__ out,
    int M, int N, int K, int ocPerChunk) {
    // [buf][A=0/B=1][256 rows * 128 B]
    __shared__ __align__(16) uint8_t lds[2][2][BM * BKB];

    const int tid  = threadIdx.x;
    const int lane = tid & 63;
    const int wid  = tid >> 6;   // 0..7
    const int wm   = wid >> 2;   // 0..1  (M half)
    const int wn   = wid & 3;    // 0..3  (N quarter)

    // T1: bijective XCD swizzle (gridDim.x % 8 == 0)
    const int nwg = gridDim.x;
    const int cpx = nwg >> 3;
    const int swz = (blockIdx.x & 7) * cpx + (blockIdx.x >> 3);
    const int nbx = N / BN;
    const int bx  = swz % nbx;
    const int by  = swz / nbx;
    const int m0  = by * BM;
    const int n0  = bx * BN;

    const int lr   = lane & 15;
    const int sw   = (lr & 7) << 4;
    const int off0 = ((lane >> 4) * 32) ^ sw;
    const int off1 = off0 ^ 16;

    f32x4 acc[8][4] = {};

    const int nkt = K / BKB;

    // stage K-tile (k-offset kt) into buffer b: 8 x gload_lds16 per thread
    auto stage = [&](int b, int kt) {
#pragma unroll
        for (int i = 0; i < 8; ++i) {
            const int idx = i * 512 + tid;                 // 0..4095
            const int row = idx >> 3;                      // 0..511
            const int col = ((idx & 7) * 16) ^ ((row & 7) << 4);
            const uint8_t* src = (i < 4)
                ? Aq + (size_t)(m0 + row) * K + kt + col
                : Bq + (size_t)(n0 + (row - 256)) * K + kt + col;
            gload_lds16(src, &lds[b][0][0] + idx * 16);
        }
    };

    // prologue: tile 0
    stage(0, 0);
    asm volatile("s_waitcnt vmcnt(0)" ::: "memory");
    __builtin_amdgcn_s_barrier();

    for (int t = 0; t < nkt; ++t) {
        const int cur = t & 1;
        const uint8_t* pa = &lds[cur][0][0] + (wm * 128 + lr) * BKB;
        const uint8_t* pb = &lds[cur][1][0] + (wn * 64  + lr) * BKB;

        // ---- issue B frags + A pairs 0,1; then next-tile staging ----
        i32x8 bv[4];
#pragma unroll
        for (int ni = 0; ni < 4; ni++)
            bv[ni] = read_frag(pb + ni * 16 * BKB, off0, off1);
        i32x8 a0 = read_frag(pa,            off0, off1);
        i32x8 a1 = read_frag(pa + 16 * BKB, off0, off1);
        i32x8 a2 = read_frag(pa + 32 * BKB, off0, off1);
        i32x8 a3 = read_frag(pa + 48 * BKB, off0, off1);
        if (t + 1 < nkt) stage(cur ^ 1, (t + 1) * BKB);

        // ---- g0: B + pair0 ready (pair1's 4 reads still in flight) ----
        WAIT_LGKM(4);
        __builtin_amdgcn_s_setprio(1);
#pragma unroll
        for (int ni = 0; ni < 4; ni++) {
            acc[0][ni] = MFMA_MX(a0, bv[ni], acc[0][ni]);
            acc[1][ni] = MFMA_MX(a1, bv[ni], acc[1][ni]);
        }
        __builtin_amdgcn_s_setprio(0);

        // ---- g1: issue pair2, wait pair1 ----
        i32x8 a4 = read_frag(pa + 64 * BKB, off0, off1);
        i32x8 a5 = read_frag(pa + 80 * BKB, off0, off1);
        WAIT_LGKM(4);
        __builtin_amdgcn_s_setprio(1);
#pragma unroll
        for (int ni = 0; ni < 4; ni++) {
            acc[2][ni] = MFMA_MX(a2, bv[ni], acc[2][ni]);
            acc[3][ni] = MFMA_MX(a3, bv[ni], acc[3][ni]);
        }
        __builtin_amdgcn_s_setprio(0);

        // ---- g2: issue pair3, wait pair2 ----
        i32x8 a6 = read_frag(pa + 96 * BKB,  off0, off1);
        i32x8 a7 = read_frag(pa + 112 * BKB, off0, off1);
        WAIT_LGKM(4);
        __builtin_amdgcn_s_setprio(1);
#pragma unroll
        for (int ni = 0; ni < 4; ni++) {
            acc[4][ni] = MFMA_MX(a4, bv[ni], acc[4][ni]);
            acc[5][ni] = MFMA_MX(a5, bv[ni], acc[5][ni]);
        }
        __builtin_amdgcn_s_setprio(0);

        // ---- g3: wait pair3 (all tile-t reads retired after this) ----
        WAIT_LGKM(0);
        __builtin_amdgcn_s_setprio(1);
#pragma unroll
        for (int ni = 0; ni < 4; ni++) {
            acc[6][ni] = MFMA_MX(a6, bv[ni], acc[6][ni]);
            acc[7][ni] = MFMA_MX(a7, bv[ni], acc[7][ni]);
        }
        __builtin_amdgcn_s_setprio(0);

        // ---- end of iter: tile t+1 must be fully in LDS before next top ----
        asm volatile("s_waitcnt vmcnt(0)" ::: "memory");
        __builtin_amdgcn_s_barrier();
    }

    // ---- epilogue: dequant + bias (C/D: col=lane&15, row=(lane>>4)*4+j) ----
    const float is = isp[0];
#pragma unroll
    for (int ni = 0; ni < 4; ni++) {
        const int cidx = n0 + wn * 64 + ni * 16 + lr;
        const float sc = is * wsc[cidx / ocPerChunk];
        const float bs = bias[cidx];
#pragma unroll
        for (int mi = 0; mi < 8; mi++) {
            const int rbase = m0 + wm * 128 + mi * 16 + (lane >> 4) * 4;
#pragma unroll
            for (int j = 0; j < 4; j++)
                out[(size_t)(rbase + j) * N + cidx] = acc[mi][ni][j] * sc + bs;
        }
    }
}

// ---------------------------------------------------------------------------
extern "C" void kernel_launch(void* const* d_in, const int* in_sizes, int n_in,
                              void* d_out, int out_size, void* d_ws, size_t ws_size,
                              hipStream_t stream) {
    const float* x        = (const float*)d_in[0];
    const float* w        = (const float*)d_in[1];
    const float* bias     = (const float*)d_in[2];
    const float* in_scale = (const float*)d_in[3];
    const float* w_scales = (const float*)d_in[4];
    float* out = (float*)d_out;

    const int N = in_sizes[2];               // 4096
    const int K = in_sizes[1] / N;           // 4096
    const int M = in_sizes[0] / K;           // 16384
    const int CHUNKS = in_sizes[4];          // 4
    const int ocPerChunk = N / CHUNKS;       // 1024

    uint8_t* xq = (uint8_t*)d_ws;            // M*K bytes
    uint8_t* wq = xq + (size_t)M * K;        // N*K bytes

    const int xn16 = (int)(((size_t)M * K) / 16);
    const int wn16 = (int)(((size_t)N * K) / 16);
    const int chunk16 = (N / CHUNKS) * K / 16;

    quant_x_kernel<<<2048, 256, 0, stream>>>(x, in_scale, (uint4*)xq, xn16);
    quant_w_kernel<<<2048, 256, 0, stream>>>(w, w_scales, (uint4*)wq, wn16, chunk16);

    const int nblk = (M / BM) * (N / BN);    // 64 * 16 = 1024
    gemm_fp8_kernel<<<dim3(nblk), 512, 0, stream>>>(xq, wq, bias, in_scale,
                                                    w_scales, out, M, N, K,
                                                    ocPerChunk);
}